// Round 1
// baseline (308.329 us; speedup 1.0000x reference)
//
#include <hip/hip_runtime.h>
#include <hip/hip_bf16.h>

// Problem constants (B,N,H,W,C) = (2,512,16,32,64)
#define B_ 2
#define N_ 512
#define M_ 512
#define C_ 64
#define O1 128
#define O2 64
#define O3 32
#define PBIG 524288.0f   // B*N*M samples for BN1/BN2
#define P3   1024.0f     // B*N samples for BN3

typedef short s8v __attribute__((ext_vector_type(8)));   // 8 bf16 (4 VGPRs)
typedef float f4v __attribute__((ext_vector_type(4)));   // MFMA accumulator

// ---- workspace layout (float-element offsets). Total ~67.7 MB. ----
#define WS_SRCN 0        //  [B][N][64]
#define WS_DSTN 65536    //  [B][M][64]
#define WS_U    131072   //  [B][N][128]
#define WS_V    262144   //  [B][M][128]
#define WS_DXY  393216   //  [B][M][2]
#define WS_COS  395264   //  [B][N][M]
#define WS_RMAX 919552   //  [B*N]
#define WS_CMAX 920576   //  [B*M] (uint, order-encoded max)
#define WS_ST1  921600   //  [16][256] BN1 partial sums
#define WS_ST2  925696   //  [16][128] BN2 partial sums
#define WS_ST3  927744   //  [16][64]  BN3 partial sums
#define WS_Z    928768   //  [B][N][32]
#define WS_X2   961536   //  bf16 [B][N][M][64] starts here

__device__ __forceinline__ unsigned fenc(float f){
  unsigned b = __float_as_uint(f);
  return (b & 0x80000000u) ? ~b : (b | 0x80000000u);
}
__device__ __forceinline__ float fdec(unsigned u){
  unsigned b = (u & 0x80000000u) ? (u & 0x7fffffffu) : ~u;
  return __uint_as_float(b);
}
__device__ __forceinline__ unsigned short f2bf(float f){
  unsigned u = __float_as_uint(f);
  unsigned r = (u + 0x7fffu + ((u >> 16) & 1u)) >> 16;   // RNE
  return (unsigned short)r;
}
__device__ __forceinline__ float bf2f(unsigned short h){
  return __uint_as_float(((unsigned)h) << 16);
}

// ---------------- K1a: per-(b,n) src normals + U ----------------
__global__ __launch_bounds__(128) void k1a(const float* __restrict__ wxyz,
    const float* __restrict__ wpts, const float* __restrict__ lz,
    const float* __restrict__ W1, float* __restrict__ ws){
  int blk = blockIdx.x; int b = blk >> 9, n = blk & 511; int t = threadIdx.x;
  int bn = b*N_ + n;
  __shared__ float wp[64]; __shared__ float sxyz[3]; __shared__ float slz; __shared__ float srn;
  if (t < 64) wp[t] = wpts[bn*64 + t];
  if (t >= 64 && t < 67) sxyz[t-64] = wxyz[bn*3 + (t-64)];
  if (t == 67) slz = lz[bn];
  __syncthreads();
  if (t < 64){
    float v = wp[t]*wp[t];
    v += __shfl_down(v,32); v += __shfl_down(v,16); v += __shfl_down(v,8);
    v += __shfl_down(v,4);  v += __shfl_down(v,2);  v += __shfl_down(v,1);
    if (t == 0) srn = 1.0f / fmaxf(sqrtf(v), 1e-12f);
  }
  __syncthreads();
  if (t < 64) ws[WS_SRCN + bn*64 + t] = wp[t]*srn;
  int o = t;
  float x = sxyz[0], y = sxyz[1], z = sxyz[2], l = slz;
  float acc = x*l*W1[0*O1+o] + y*l*W1[1*O1+o] + z*l*W1[2*O1+o]
            + wp[0]*W1[3*O1+o] + wp[1]*W1[4*O1+o]
            + x*W1[7*O1+o] + y*W1[8*O1+o];
  #pragma unroll 8
  for (int c = 0; c < 64; ++c) acc += wp[c]*W1[(10+c)*O1+o];
  ws[WS_U + bn*O1 + o] = acc;
}

// ---------------- K1b: per-(b,m) dst normals + V + dst_xy ----------------
__global__ __launch_bounds__(128) void k1b(const float* __restrict__ rf3,
    const float* __restrict__ rf3i, const float* __restrict__ W1, float* __restrict__ ws){
  int blk = blockIdx.x; int b = blk >> 9, m = blk & 511; int t = threadIdx.x;
  int bm = b*M_ + m;
  __shared__ float rf[64]; __shared__ float sdx, sdy, srn;
  if (t < 64) rf[t] = rf3[(b*64 + t)*512 + m];
  if (t == 64) sdx = rf3i[(b*3 + 0)*512 + m];
  if (t == 65) sdy = rf3i[(b*3 + 1)*512 + m];
  __syncthreads();
  if (t < 64){
    float v = rf[t]*rf[t];
    v += __shfl_down(v,32); v += __shfl_down(v,16); v += __shfl_down(v,8);
    v += __shfl_down(v,4);  v += __shfl_down(v,2);  v += __shfl_down(v,1);
    if (t == 0) srn = 1.0f / fmaxf(sqrtf(v), 1e-12f);
  }
  __syncthreads();
  if (t < 64) ws[WS_DSTN + bm*64 + t] = rf[t]*srn;
  if (t == 0){ ws[WS_DXY + bm*2+0] = sdx; ws[WS_DXY + bm*2+1] = sdy; }
  int o = t;
  float acc = sdx*(W1[5*O1+o] - W1[7*O1+o]) + sdy*(W1[6*O1+o] - W1[8*O1+o]);
  #pragma unroll 8
  for (int c = 0; c < 64; ++c) acc += rf[c]*W1[(74+c)*O1+o];
  ws[WS_V + bm*O1 + o] = acc;
}

// ---------------- K2: cos matrix + rowmax + colmax(atomic) ----------------
__global__ __launch_bounds__(256) void k2(float* __restrict__ ws){
  int blk = blockIdx.x; int b = blk >> 9, n = blk & 511; int t = threadIdx.x;
  int bn = b*N_ + n;
  __shared__ __align__(16) float sn[64];
  __shared__ float dnt[64*65];   // +1 pad: conflict-free row reads
  if (t < 64) sn[t] = ws[WS_SRCN + bn*64 + t];
  unsigned* cmax = (unsigned*)ws + WS_CMAX;
  float lmax = -1e30f;
  for (int chunk = 0; chunk < 8; ++chunk){
    int m0 = chunk*64;
    __syncthreads();
    for (int idx = t; idx < 4096; idx += 256){
      int mm = idx >> 6, c = idx & 63;
      dnt[mm*65 + c] = ws[WS_DSTN + (b*M_ + m0 + mm)*64 + c];
    }
    __syncthreads();
    if (t < 64){
      float d = 0.f;
      #pragma unroll
      for (int c = 0; c < 64; ++c) d += sn[c]*dnt[t*65 + c];
      int m = m0 + t;
      ws[WS_COS + bn*M_ + m] = d;
      atomicMax(&cmax[b*M_ + m], fenc(d));
      lmax = fmaxf(lmax, d);
    }
  }
  if (t < 64){
    lmax = fmaxf(lmax, __shfl_xor(lmax,32)); lmax = fmaxf(lmax, __shfl_xor(lmax,16));
    lmax = fmaxf(lmax, __shfl_xor(lmax,8));  lmax = fmaxf(lmax, __shfl_xor(lmax,4));
    lmax = fmaxf(lmax, __shfl_xor(lmax,2));  lmax = fmaxf(lmax, __shfl_xor(lmax,1));
    if (t == 0) ws[WS_RMAX + bn] = lmax;
  }
}

// ---------------- K3: BN1 stats via rank-structured recompute ----------------
__global__ __launch_bounds__(128) void k3(const float* __restrict__ wxyz,
    const float* __restrict__ W1, const float* __restrict__ b1, float* __restrict__ ws){
  int blk = blockIdx.x; int b = blk >> 9, n = blk & 511; int t = threadIdx.x;
  int bn = b*N_ + n;
  __shared__ float s_en[512], s_s1[512], s_s2[512];
  __shared__ float sx, sy, srm;
  if (t == 0){ sx = wxyz[bn*3+0]; sy = wxyz[bn*3+1]; srm = ws[WS_RMAX+bn]; }
  __syncthreads();
  const unsigned* cmax = (const unsigned*)ws + WS_CMAX;
  #pragma unroll
  for (int i = 0; i < 4; ++i){
    int m = t + i*128;
    float dx = ws[WS_DXY + (b*M_+m)*2+0], dy = ws[WS_DXY + (b*M_+m)*2+1];
    float ex = sx-dx, ey = sy-dy;
    s_en[m] = sqrtf(ex*ex + ey*ey);
    float cv = ws[WS_COS + bn*M_ + m];
    s_s1[m] = cv/(srm + 1e-6f);
    s_s2[m] = cv/(fdec(cmax[b*M_+m]) + 1e-10f);
  }
  __syncthreads();
  int o = t;
  float u  = ws[WS_U + bn*O1 + o] + b1[o];
  float w9 = W1[9*O1+o], wa = W1[138*O1+o], wb = W1[139*O1+o];
  float sum = 0.f, ssq = 0.f;
  const float* Vp = ws + WS_V + b*M_*O1 + o;
  #pragma unroll 8
  for (int m = 0; m < 512; ++m){
    float xv = u + Vp[m*O1] + s_en[m]*w9 + s_s1[m]*wa + s_s2[m]*wb;
    sum += xv; ssq += xv*xv;
  }
  int rep = blk & 15;
  atomicAdd(&ws[WS_ST1 + rep*256 + o], sum);
  atomicAdd(&ws[WS_ST1 + rep*256 + 128 + o], ssq);
}

// ---------------- K4: h = ReLU(BN1(x1)) tile -> MFMA @ W2 -> x2(bf16) + BN2 stats ----
#define HROW 136   // 128 + 8 pad: 272B row stride = 16B-aligned, 2-way-bank (free)
__global__ __launch_bounds__(256) void k4(const float* __restrict__ wxyz,
    const float* __restrict__ W1, const float* __restrict__ b1,
    const float* __restrict__ g1, const float* __restrict__ be1,
    const float* __restrict__ W2, float* __restrict__ ws){
  int blk = blockIdx.x;
  int b = blk >> 11; int rem = blk & 2047; int n = rem >> 2; int mc = rem & 3;
  int t = threadIdx.x; int bn = b*N_ + n; int m0 = mc*128;
  __shared__ unsigned short hA[128*HROW];
  __shared__ unsigned short wB[64*HROW];
  __shared__ float s_en[128], s_s1[128], s_s2[128];
  __shared__ float sP0[128], sA1[128], sW9[128], sWa[128], sWb[128];
  __shared__ float ls[64], lq[64];
  __shared__ float sx, sy, srm;
  if (t == 128) sx = wxyz[bn*3+0];
  if (t == 129) sy = wxyz[bn*3+1];
  if (t == 130) srm = ws[WS_RMAX+bn];
  if (t < 64){ ls[t] = 0.f; lq[t] = 0.f; }
  if (t < 128){
    int o = t; float s = 0.f, q = 0.f;
    #pragma unroll
    for (int r = 0; r < 16; ++r){ s += ws[WS_ST1 + r*256 + o]; q += ws[WS_ST1 + r*256 + 128 + o]; }
    float mu = s/PBIG; float var = q/PBIG - mu*mu;
    float istd = rsqrtf(var + 1e-5f);
    float A1 = g1[o]*istd; float C1 = be1[o] - mu*A1;
    float u = ws[WS_U + bn*O1 + o] + b1[o];
    sP0[o] = u*A1 + C1; sA1[o] = A1;
    sW9[o] = W1[9*O1+o]*A1; sWa[o] = W1[138*O1+o]*A1; sWb[o] = W1[139*O1+o]*A1;
  }
  for (int idx = t; idx < 8192; idx += 256){   // stage W2^T bf16
    int o = idx >> 6, c = idx & 63;
    wB[c*HROW + o] = f2bf(W2[idx]);
  }
  __syncthreads();
  if (t < 128){
    int m = m0 + t;
    float dx = ws[WS_DXY + (b*M_+m)*2+0], dy = ws[WS_DXY + (b*M_+m)*2+1];
    float ex = sx-dx, ey = sy-dy;
    s_en[t] = sqrtf(ex*ex + ey*ey);
    float cv = ws[WS_COS + bn*M_ + m];
    s_s1[t] = cv/(srm + 1e-6f);
    s_s2[t] = cv/(fdec(((const unsigned*)ws)[WS_CMAX + b*M_+m]) + 1e-10f);
  }
  __syncthreads();
  {
    int lane = t & 63, g = t >> 6;
    const float* Vb = ws + WS_V + (size_t)(b*M_ + m0)*O1;
    int o0 = 2*lane;
    #pragma unroll 8
    for (int i = 0; i < 32; ++i){
      int ml = g + 4*i;
      float en = s_en[ml], s1 = s_s1[ml], s2 = s_s2[ml];
      float2 v = *(const float2*)(Vb + ml*O1 + o0);
      float h0 = fmaxf(sP0[o0]   + v.x*sA1[o0]   + en*sW9[o0]   + s1*sWa[o0]   + s2*sWb[o0],   0.f);
      float h1 = fmaxf(sP0[o0+1] + v.y*sA1[o0+1] + en*sW9[o0+1] + s1*sWa[o0+1] + s2*sWb[o0+1], 0.f);
      unsigned pack = (unsigned)f2bf(h0) | ((unsigned)f2bf(h1) << 16);
      *(unsigned*)&hA[ml*HROW + o0] = pack;
    }
  }
  __syncthreads();
  int lane = t & 63, w = t >> 6;
  int l16 = lane & 15, quad = lane >> 4;
  f4v acc[2][4];
  #pragma unroll
  for (int i = 0; i < 2; ++i)
    #pragma unroll
    for (int j = 0; j < 4; ++j) acc[i][j] = (f4v){0.f,0.f,0.f,0.f};
  int ar0 = (w*32 + l16)*HROW, ar1 = (w*32 + 16 + l16)*HROW;
  #pragma unroll
  for (int k0 = 0; k0 < 128; k0 += 32){
    int ko = k0 + quad*8;
    s8v a0 = *(const s8v*)&hA[ar0 + ko];
    s8v a1 = *(const s8v*)&hA[ar1 + ko];
    #pragma unroll
    for (int ct = 0; ct < 4; ++ct){
      s8v bb = *(const s8v*)&wB[(ct*16 + l16)*HROW + ko];
      acc[0][ct] = __builtin_amdgcn_mfma_f32_16x16x32_bf16(a0, bb, acc[0][ct], 0,0,0);
      acc[1][ct] = __builtin_amdgcn_mfma_f32_16x16x32_bf16(a1, bb, acc[1][ct], 0,0,0);
    }
  }
  unsigned short* x2p = (unsigned short*)(ws + WS_X2);
  size_t xbase = (size_t)bn*M_*O2;
  #pragma unroll
  for (int ct = 0; ct < 4; ++ct){
    int c = ct*16 + l16;
    float s = 0.f, q = 0.f;
    #pragma unroll
    for (int mt = 0; mt < 2; ++mt){
      #pragma unroll
      for (int r = 0; r < 4; ++r){
        float v = acc[mt][ct][r];
        int m = m0 + w*32 + mt*16 + quad*4 + r;
        x2p[xbase + (size_t)m*O2 + c] = f2bf(v);
        s += v; q += v*v;
      }
    }
    s += __shfl_xor(s,16); s += __shfl_xor(s,32);
    q += __shfl_xor(q,16); q += __shfl_xor(q,32);
    if (quad == 0){ atomicAdd(&ls[c], s); atomicAdd(&lq[c], q); }
  }
  __syncthreads();
  int rep = blk & 15;
  if (t < 64) atomicAdd(&ws[WS_ST2 + rep*128 + t], ls[t]);
  else if (t < 128) atomicAdd(&ws[WS_ST2 + rep*128 + t], lq[t-64]);
}

// ---------------- K5: BN2 + softmax-attention pool + head L1 + BN3 stats ----------------
__global__ __launch_bounds__(256) void k5(const float* __restrict__ g2,
    const float* __restrict__ be2, const float* __restrict__ M1w,
    const float* __restrict__ M1b, float* __restrict__ ws){
  int blk = blockIdx.x; int b = blk >> 9, n = blk & 511; int t = threadIdx.x;
  int bn = b*N_ + n;
  __shared__ float sa2[64], sc2[64];
  __shared__ float s_mx[512], s_aw[512];
  __shared__ float red[256];
  __shared__ float satt[4*64];
  __shared__ float s_att[64];
  __shared__ float sgmax, sinvS;
  if (t < 64){
    float s = 0.f, q = 0.f;
    #pragma unroll
    for (int r = 0; r < 16; ++r){ s += ws[WS_ST2 + r*128 + t]; q += ws[WS_ST2 + r*128 + 64 + t]; }
    float mu = s/PBIG, var = q/PBIG - mu*mu;
    float istd = rsqrtf(var + 1e-5f);
    float A2 = g2[t]*istd;
    sa2[t] = A2; sc2[t] = be2[t] - mu*A2;
  }
  __syncthreads();
  const unsigned short* x2p = (const unsigned short*)(ws + WS_X2) + (size_t)bn*M_*O2;
  int lane = t & 63, w = t >> 6;
  {
    float A2 = sa2[lane], C2 = sc2[lane];
    for (int k = 0; k < 128; ++k){
      int m = w*128 + k;
      float v = fmaxf(bf2f(x2p[(size_t)m*O2 + lane])*A2 + C2, 0.f);
      v = fmaxf(v, __shfl_xor(v,32)); v = fmaxf(v, __shfl_xor(v,16));
      v = fmaxf(v, __shfl_xor(v,8));  v = fmaxf(v, __shfl_xor(v,4));
      v = fmaxf(v, __shfl_xor(v,2));  v = fmaxf(v, __shfl_xor(v,1));
      if (lane == 0) s_mx[m] = v;
    }
  }
  __syncthreads();
  red[t] = fmaxf(s_mx[t], s_mx[t+256]);
  __syncthreads();
  for (int s = 128; s > 0; s >>= 1){ if (t < s) red[t] = fmaxf(red[t], red[t+s]); __syncthreads(); }
  if (t == 0) sgmax = red[0];
  __syncthreads();
  float e0 = expf(s_mx[t] - sgmax), e1 = expf(s_mx[t+256] - sgmax);
  s_aw[t] = e0; s_aw[t+256] = e1;
  red[t] = e0 + e1;
  __syncthreads();
  for (int s = 128; s > 0; s >>= 1){ if (t < s) red[t] += red[t+s]; __syncthreads(); }
  if (t == 0) sinvS = 1.0f / red[0];
  __syncthreads();
  s_aw[t] *= sinvS; s_aw[t+256] *= sinvS;
  __syncthreads();
  {
    int c = t & 63, g = t >> 6;
    float A2 = sa2[c], C2 = sc2[c];
    float acc = 0.f;
    for (int k = 0; k < 128; ++k){
      int m = g*128 + k;
      acc += s_aw[m]*fmaxf(bf2f(x2p[(size_t)m*O2 + c])*A2 + C2, 0.f);
    }
    satt[g*64 + c] = acc;
  }
  __syncthreads();
  if (t < 64) s_att[t] = satt[t] + satt[64+t] + satt[128+t] + satt[192+t];
  __syncthreads();
  if (t < 32){
    float z = M1b[t];
    #pragma unroll 8
    for (int c = 0; c < 64; ++c) z += s_att[c]*M1w[c*32 + t];
    ws[WS_Z + bn*32 + t] = z;
    int rep = blk & 15;
    atomicAdd(&ws[WS_ST3 + rep*64 + t], z);
    atomicAdd(&ws[WS_ST3 + rep*64 + 32 + t], z*z);
  }
}

// ---------------- K6: BN3 + head L2 -> logits ----------------
__global__ __launch_bounds__(256) void k6(const float* __restrict__ M1g,
    const float* __restrict__ M1be, const float* __restrict__ M2w,
    const float* __restrict__ M2b, const float* __restrict__ ws, float* __restrict__ out){
  int t = threadIdx.x; int s = blockIdx.x*256 + t;
  __shared__ float sa3[32], sc3[32];
  if (t < 32){
    float su = 0.f, q = 0.f;
    #pragma unroll
    for (int r = 0; r < 16; ++r){ su += ws[WS_ST3 + r*64 + t]; q += ws[WS_ST3 + r*64 + 32 + t]; }
    float mu = su/P3, var = q/P3 - mu*mu;
    float istd = rsqrtf(var + 1e-5f);
    float A3 = M1g[t]*istd;
    sa3[t] = A3; sc3[t] = M1be[t] - mu*A3;
  }
  __syncthreads();
  float a0 = M2b[0], a1 = M2b[1];
  #pragma unroll
  for (int j = 0; j < 32; ++j){
    float y = fmaxf(ws[WS_Z + s*32 + j]*sa3[j] + sc3[j], 0.f);
    a0 += y*M2w[j*2+0]; a1 += y*M2w[j*2+1];
  }
  out[s*2+0] = a0; out[s*2+1] = a1;
}

extern "C" void kernel_launch(void* const* d_in, const int* in_sizes, int n_in,
                              void* d_out, int out_size, void* d_ws, size_t ws_size,
                              hipStream_t stream){
  const float* wxyz = (const float*)d_in[0];
  const float* wpts = (const float*)d_in[1];
  const float* rf3  = (const float*)d_in[2];
  const float* rf3i = (const float*)d_in[3];
  const float* lz   = (const float*)d_in[4];
  const float* W1   = (const float*)d_in[5];
  const float* b1   = (const float*)d_in[6];
  const float* g1   = (const float*)d_in[7];
  const float* be1  = (const float*)d_in[8];
  const float* W2   = (const float*)d_in[9];
  const float* g2   = (const float*)d_in[11];
  const float* be2  = (const float*)d_in[12];
  const float* M1w  = (const float*)d_in[13];
  const float* M1b  = (const float*)d_in[14];
  const float* M1g  = (const float*)d_in[15];
  const float* M1be = (const float*)d_in[16];
  const float* M2w  = (const float*)d_in[17];
  const float* M2b  = (const float*)d_in[18];
  float* ws  = (float*)d_ws;
  float* out = (float*)d_out;
  // zero colmax (encoded-min) + BN stat accumulators (ws is poisoned 0xAA each call)
  hipMemsetAsync(ws + WS_CMAX, 0, (1024 + 4096 + 2048 + 1024)*sizeof(float), stream);
  k1a<<<1024,128,0,stream>>>(wxyz, wpts, lz, W1, ws);
  k1b<<<1024,128,0,stream>>>(rf3, rf3i, W1, ws);
  k2 <<<1024,256,0,stream>>>(ws);
  k3 <<<1024,128,0,stream>>>(wxyz, W1, b1, ws);
  k4 <<<4096,256,0,stream>>>(wxyz, W1, b1, g1, be1, W2, ws);
  k5 <<<1024,256,0,stream>>>(g2, be2, M1w, M1b, ws);
  k6 <<<4,256,0,stream>>>(M1g, M1be, M2w, M2b, ws, out);
}

// Round 2
// 247.627 us; speedup vs baseline: 1.2451x; 1.2451x over previous
//
#include <hip/hip_runtime.h>
#include <hip/hip_bf16.h>

// Problem constants (B,N,H,W,C) = (2,512,16,32,64)
#define B_ 2
#define N_ 512
#define M_ 512
#define C_ 64
#define O1 128
#define O2 64
#define O3 32
#define PBIG 524288.0f   // B*N*M samples for BN1/BN2
#define P3   1024.0f     // B*N samples for BN3

typedef short s8v __attribute__((ext_vector_type(8)));   // 8 bf16 (4 VGPRs)
typedef float f4v __attribute__((ext_vector_type(4)));   // MFMA accumulator

// ---- workspace layout (float-element offsets). Total ~67.7 MB. ----
#define WS_SRCN 0        //  [B][N][64]
#define WS_DSTN 65536    //  [B][M][64]
#define WS_U    131072   //  [B][N][128]
#define WS_V    262144   //  [B][M][128]
#define WS_DXY  393216   //  [B][M][2]
#define WS_COS  395264   //  [B][N][M]
#define WS_RMAX 919552   //  [B*N]
#define WS_CMAX 920576   //  [B*M] (uint, order-encoded max)
#define WS_ST1  921600   //  [16][256] BN1 partial sums
#define WS_ST2  925696   //  [16][128] BN2 partial sums
#define WS_ST3  927744   //  [16][64]  BN3 partial sums
#define WS_Z    928768   //  [B][N][32]
#define WS_X2   961536   //  bf16 [B][N][M][64] starts here

__device__ __forceinline__ unsigned fenc(float f){
  unsigned b = __float_as_uint(f);
  return (b & 0x80000000u) ? ~b : (b | 0x80000000u);
}
__device__ __forceinline__ float fdec(unsigned u){
  unsigned b = (u & 0x80000000u) ? (u & 0x7fffffffu) : ~u;
  return __uint_as_float(b);
}
__device__ __forceinline__ unsigned short f2bf(float f){
  unsigned u = __float_as_uint(f);
  unsigned r = (u + 0x7fffu + ((u >> 16) & 1u)) >> 16;   // RNE
  return (unsigned short)r;
}
__device__ __forceinline__ float bf2f(unsigned short h){
  return __uint_as_float(((unsigned)h) << 16);
}

// ---------------- K1a: per-(b,n) src normals + U ----------------
__global__ __launch_bounds__(128) void k1a(const float* __restrict__ wxyz,
    const float* __restrict__ wpts, const float* __restrict__ lz,
    const float* __restrict__ W1, float* __restrict__ ws){
  int blk = blockIdx.x; int b = blk >> 9, n = blk & 511; int t = threadIdx.x;
  int bn = b*N_ + n;
  __shared__ float wp[64]; __shared__ float sxyz[3]; __shared__ float slz; __shared__ float srn;
  if (t < 64) wp[t] = wpts[bn*64 + t];
  if (t >= 64 && t < 67) sxyz[t-64] = wxyz[bn*3 + (t-64)];
  if (t == 67) slz = lz[bn];
  __syncthreads();
  if (t < 64){
    float v = wp[t]*wp[t];
    v += __shfl_down(v,32); v += __shfl_down(v,16); v += __shfl_down(v,8);
    v += __shfl_down(v,4);  v += __shfl_down(v,2);  v += __shfl_down(v,1);
    if (t == 0) srn = 1.0f / fmaxf(sqrtf(v), 1e-12f);
  }
  __syncthreads();
  if (t < 64) ws[WS_SRCN + bn*64 + t] = wp[t]*srn;
  int o = t;
  float x = sxyz[0], y = sxyz[1], z = sxyz[2], l = slz;
  float acc = x*l*W1[0*O1+o] + y*l*W1[1*O1+o] + z*l*W1[2*O1+o]
            + wp[0]*W1[3*O1+o] + wp[1]*W1[4*O1+o]
            + x*W1[7*O1+o] + y*W1[8*O1+o];
  #pragma unroll 8
  for (int c = 0; c < 64; ++c) acc += wp[c]*W1[(10+c)*O1+o];
  ws[WS_U + bn*O1 + o] = acc;
}

// ---------------- K1b: per-(b,m) dst normals + V + dst_xy ----------------
__global__ __launch_bounds__(128) void k1b(const float* __restrict__ rf3,
    const float* __restrict__ rf3i, const float* __restrict__ W1, float* __restrict__ ws){
  int blk = blockIdx.x; int b = blk >> 9, m = blk & 511; int t = threadIdx.x;
  int bm = b*M_ + m;
  __shared__ float rf[64]; __shared__ float sdx, sdy, srn;
  if (t < 64) rf[t] = rf3[(b*64 + t)*512 + m];
  if (t == 64) sdx = rf3i[(b*3 + 0)*512 + m];
  if (t == 65) sdy = rf3i[(b*3 + 1)*512 + m];
  __syncthreads();
  if (t < 64){
    float v = rf[t]*rf[t];
    v += __shfl_down(v,32); v += __shfl_down(v,16); v += __shfl_down(v,8);
    v += __shfl_down(v,4);  v += __shfl_down(v,2);  v += __shfl_down(v,1);
    if (t == 0) srn = 1.0f / fmaxf(sqrtf(v), 1e-12f);
  }
  __syncthreads();
  if (t < 64) ws[WS_DSTN + bm*64 + t] = rf[t]*srn;
  if (t == 0){ ws[WS_DXY + bm*2+0] = sdx; ws[WS_DXY + bm*2+1] = sdy; }
  int o = t;
  float acc = sdx*(W1[5*O1+o] - W1[7*O1+o]) + sdy*(W1[6*O1+o] - W1[8*O1+o]);
  #pragma unroll 8
  for (int c = 0; c < 64; ++c) acc += rf[c]*W1[(74+c)*O1+o];
  ws[WS_V + bm*O1 + o] = acc;
}

// ---------------- K2: cos matrix + rowmax + colmax(atomic), all 256 threads ----------------
__global__ __launch_bounds__(256) void k2(float* __restrict__ ws){
  int blk = blockIdx.x; int b = blk >> 9, n = blk & 511; int t = threadIdx.x;
  int bn = b*N_ + n;
  __shared__ __align__(16) float sn[64];
  __shared__ float dnt[64*65];   // +1 pad: conflict-free row reads
  __shared__ float part[4*64];
  if (t < 64) sn[t] = ws[WS_SRCN + bn*64 + t];
  unsigned* cmax = (unsigned*)ws + WS_CMAX;
  float lmax = -1e30f;
  for (int chunk = 0; chunk < 8; ++chunk){
    __syncthreads();
    const float4* src = (const float4*)(ws + WS_DSTN + (size_t)(b*M_ + chunk*64)*64);
    #pragma unroll
    for (int i = 0; i < 4; ++i){
      float4 v = src[t + i*256];
      int base = (t + i*256)*4; int mm = base >> 6, c = base & 63;
      float* dp = &dnt[mm*65 + c];
      dp[0]=v.x; dp[1]=v.y; dp[2]=v.z; dp[3]=v.w;
    }
    __syncthreads();
    {
      int mm = t & 63, cg = t >> 6;
      const float* dr = &dnt[mm*65 + cg*16];
      const float* sr = &sn[cg*16];
      float p = 0.f;
      #pragma unroll
      for (int k = 0; k < 16; ++k) p += sr[k]*dr[k];
      part[cg*64 + mm] = p;
    }
    __syncthreads();
    if (t < 64){
      float d = part[t] + part[64+t] + part[128+t] + part[192+t];
      int m = chunk*64 + t;
      ws[WS_COS + bn*M_ + m] = d;
      atomicMax(&cmax[b*M_ + m], fenc(d));
      lmax = fmaxf(lmax, d);
    }
  }
  if (t < 64){
    lmax = fmaxf(lmax, __shfl_xor(lmax,32)); lmax = fmaxf(lmax, __shfl_xor(lmax,16));
    lmax = fmaxf(lmax, __shfl_xor(lmax,8));  lmax = fmaxf(lmax, __shfl_xor(lmax,4));
    lmax = fmaxf(lmax, __shfl_xor(lmax,2));  lmax = fmaxf(lmax, __shfl_xor(lmax,1));
    if (t == 0) ws[WS_RMAX + bn] = lmax;
  }
}

// ---------------- K3: BN1 stats via rank-structured recompute ----------------
__global__ __launch_bounds__(128) void k3(const float* __restrict__ wxyz,
    const float* __restrict__ W1, const float* __restrict__ b1, float* __restrict__ ws){
  int blk = blockIdx.x; int b = blk >> 9, n = blk & 511; int t = threadIdx.x;
  int bn = b*N_ + n;
  __shared__ float s_en[512], s_s1[512], s_s2[512];
  __shared__ float sx, sy, srm;
  if (t == 0){ sx = wxyz[bn*3+0]; sy = wxyz[bn*3+1]; srm = ws[WS_RMAX+bn]; }
  __syncthreads();
  const unsigned* cmax = (const unsigned*)ws + WS_CMAX;
  #pragma unroll
  for (int i = 0; i < 4; ++i){
    int m = t + i*128;
    float dx = ws[WS_DXY + (b*M_+m)*2+0], dy = ws[WS_DXY + (b*M_+m)*2+1];
    float ex = sx-dx, ey = sy-dy;
    s_en[m] = sqrtf(ex*ex + ey*ey);
    float cv = ws[WS_COS + bn*M_ + m];
    s_s1[m] = cv/(srm + 1e-6f);
    s_s2[m] = cv/(fdec(cmax[b*M_+m]) + 1e-10f);
  }
  __syncthreads();
  int o = t;
  float u  = ws[WS_U + bn*O1 + o] + b1[o];
  float w9 = W1[9*O1+o], wa = W1[138*O1+o], wb = W1[139*O1+o];
  float sum = 0.f, ssq = 0.f;
  const float* Vp = ws + WS_V + b*M_*O1 + o;
  #pragma unroll 8
  for (int m = 0; m < 512; ++m){
    float xv = u + Vp[m*O1] + s_en[m]*w9 + s_s1[m]*wa + s_s2[m]*wb;
    sum += xv; ssq += xv*xv;
  }
  int rep = blk & 15;
  atomicAdd(&ws[WS_ST1 + rep*256 + o], sum);
  atomicAdd(&ws[WS_ST1 + rep*256 + 128 + o], ssq);
}

// ---------------- K4: h = ReLU(BN1(x1)) tile -> MFMA @ W2 -> x2(bf16) + BN2 stats ----
#define HROW 136   // 128 + 8 pad: 272B row stride = 16B-aligned, 2-way-bank (free)
__global__ __launch_bounds__(256) void k4(const float* __restrict__ wxyz,
    const float* __restrict__ W1, const float* __restrict__ b1,
    const float* __restrict__ g1, const float* __restrict__ be1,
    const float* __restrict__ W2, float* __restrict__ ws){
  int blk = blockIdx.x;
  int b = blk >> 11; int rem = blk & 2047; int n = rem >> 2; int mc = rem & 3;
  int t = threadIdx.x; int bn = b*N_ + n; int m0 = mc*128;
  __shared__ unsigned short hA[128*HROW];
  __shared__ unsigned short wB[64*HROW];
  __shared__ float s_en[128], s_s1[128], s_s2[128];
  __shared__ float sP0[128], sA1[128], sW9[128], sWa[128], sWb[128];
  __shared__ float ls[64], lq[64];
  __shared__ float sx, sy, srm;
  if (t == 128) sx = wxyz[bn*3+0];
  if (t == 129) sy = wxyz[bn*3+1];
  if (t == 130) srm = ws[WS_RMAX+bn];
  if (t < 64){ ls[t] = 0.f; lq[t] = 0.f; }
  if (t < 128){
    int o = t; float s = 0.f, q = 0.f;
    #pragma unroll
    for (int r = 0; r < 16; ++r){ s += ws[WS_ST1 + r*256 + o]; q += ws[WS_ST1 + r*256 + 128 + o]; }
    float mu = s/PBIG; float var = q/PBIG - mu*mu;
    float istd = rsqrtf(var + 1e-5f);
    float A1 = g1[o]*istd; float C1 = be1[o] - mu*A1;
    float u = ws[WS_U + bn*O1 + o] + b1[o];
    sP0[o] = u*A1 + C1; sA1[o] = A1;
    sW9[o] = W1[9*O1+o]*A1; sWa[o] = W1[138*O1+o]*A1; sWb[o] = W1[139*O1+o]*A1;
  }
  for (int idx = t; idx < 8192; idx += 256){   // stage W2^T bf16
    int o = idx >> 6, c = idx & 63;
    wB[c*HROW + o] = f2bf(W2[idx]);
  }
  __syncthreads();
  if (t < 128){
    int m = m0 + t;
    float dx = ws[WS_DXY + (b*M_+m)*2+0], dy = ws[WS_DXY + (b*M_+m)*2+1];
    float ex = sx-dx, ey = sy-dy;
    s_en[t] = sqrtf(ex*ex + ey*ey);
    float cv = ws[WS_COS + bn*M_ + m];
    s_s1[t] = cv/(srm + 1e-6f);
    s_s2[t] = cv/(fdec(((const unsigned*)ws)[WS_CMAX + b*M_+m]) + 1e-10f);
  }
  __syncthreads();
  {
    int lane = t & 63, g = t >> 6;
    const float* Vb = ws + WS_V + (size_t)(b*M_ + m0)*O1;
    int o0 = 2*lane;
    #pragma unroll 8
    for (int i = 0; i < 32; ++i){
      int ml = g + 4*i;
      float en = s_en[ml], s1 = s_s1[ml], s2 = s_s2[ml];
      float2 v = *(const float2*)(Vb + ml*O1 + o0);
      float h0 = fmaxf(sP0[o0]   + v.x*sA1[o0]   + en*sW9[o0]   + s1*sWa[o0]   + s2*sWb[o0],   0.f);
      float h1 = fmaxf(sP0[o0+1] + v.y*sA1[o0+1] + en*sW9[o0+1] + s1*sWa[o0+1] + s2*sWb[o0+1], 0.f);
      unsigned pack = (unsigned)f2bf(h0) | ((unsigned)f2bf(h1) << 16);
      *(unsigned*)&hA[ml*HROW + o0] = pack;
    }
  }
  __syncthreads();
  int lane = t & 63, w = t >> 6;
  int l16 = lane & 15, quad = lane >> 4;
  f4v acc[2][4];
  #pragma unroll
  for (int i = 0; i < 2; ++i)
    #pragma unroll
    for (int j = 0; j < 4; ++j) acc[i][j] = (f4v){0.f,0.f,0.f,0.f};
  int ar0 = (w*32 + l16)*HROW, ar1 = (w*32 + 16 + l16)*HROW;
  #pragma unroll
  for (int k0 = 0; k0 < 128; k0 += 32){
    int ko = k0 + quad*8;
    s8v a0 = *(const s8v*)&hA[ar0 + ko];
    s8v a1 = *(const s8v*)&hA[ar1 + ko];
    #pragma unroll
    for (int ct = 0; ct < 4; ++ct){
      s8v bb = *(const s8v*)&wB[(ct*16 + l16)*HROW + ko];
      acc[0][ct] = __builtin_amdgcn_mfma_f32_16x16x32_bf16(a0, bb, acc[0][ct], 0,0,0);
      acc[1][ct] = __builtin_amdgcn_mfma_f32_16x16x32_bf16(a1, bb, acc[1][ct], 0,0,0);
    }
  }
  unsigned short* x2p = (unsigned short*)(ws + WS_X2);
  size_t xbase = (size_t)bn*M_*O2;
  #pragma unroll
  for (int ct = 0; ct < 4; ++ct){
    int c = ct*16 + l16;
    float s = 0.f, q = 0.f;
    #pragma unroll
    for (int mt = 0; mt < 2; ++mt){
      #pragma unroll
      for (int r = 0; r < 4; ++r){
        float v = acc[mt][ct][r];
        int m = m0 + w*32 + mt*16 + quad*4 + r;
        x2p[xbase + (size_t)m*O2 + c] = f2bf(v);
        s += v; q += v*v;
      }
    }
    s += __shfl_xor(s,16); s += __shfl_xor(s,32);
    q += __shfl_xor(q,16); q += __shfl_xor(q,32);
    if (quad == 0){ atomicAdd(&ls[c], s); atomicAdd(&lq[c], q); }
  }
  __syncthreads();
  int rep = blk & 15;
  if (t < 64) atomicAdd(&ws[WS_ST2 + rep*128 + t], ls[t]);
  else if (t < 128) atomicAdd(&ws[WS_ST2 + rep*128 + t], lq[t-64]);
}

// ---------------- K5: BN2 + softmax-attention pool + head L1 + BN3 stats ----------------
// x2 tile held in registers: thread owns 8 channels x 32 rows (16 x 16B loads).
__global__ __launch_bounds__(256) void k5(const float* __restrict__ g2,
    const float* __restrict__ be2, const float* __restrict__ M1w,
    const float* __restrict__ M1b, float* __restrict__ ws){
  int blk = blockIdx.x; int b = blk >> 9, n = blk & 511; int t = threadIdx.x;
  int bn = b*N_ + n;
  __shared__ float sa2[64], sc2[64];
  __shared__ float s_mx[512];
  __shared__ float s_aw[512];
  __shared__ float red[256];
  __shared__ float part[32*64];
  __shared__ float s_att[64];
  __shared__ float sgmax, sinvS;
  if (t < 64){
    float s = 0.f, q = 0.f;
    #pragma unroll
    for (int r = 0; r < 16; ++r){ s += ws[WS_ST2 + r*128 + t]; q += ws[WS_ST2 + r*128 + 64 + t]; }
    float mu = s/PBIG, var = q/PBIG - mu*mu;
    float istd = rsqrtf(var + 1e-5f);
    float A2 = g2[t]*istd;
    sa2[t] = A2; sc2[t] = be2[t] - mu*A2;
  }
  __syncthreads();
  int j8 = t & 7, r32 = t >> 3;
  int c0 = j8*8;
  float a2r[8], c2r[8];
  #pragma unroll
  for (int j = 0; j < 8; ++j){ a2r[j] = sa2[c0+j]; c2r[j] = sc2[c0+j]; }
  const unsigned short* xp = (const unsigned short*)(ws + WS_X2) + (size_t)bn*M_*O2;
  // Load entire tile slice into registers: 16 x 16B coalesced (wave covers 1KB contiguous).
  s8v xv[16];
  #pragma unroll
  for (int s = 0; s < 16; ++s)
    xv[s] = *(const s8v*)(xp + (size_t)(s*32 + r32)*64 + c0);
  // Pass A: per-row max of relu(A2*x+C2); 3 shuffles across the 8-lane channel group.
  #pragma unroll
  for (int s = 0; s < 16; ++s){
    float mx = 0.f;  // relu output >= 0
    #pragma unroll
    for (int j = 0; j < 8; ++j){
      float x = bf2f((unsigned short)xv[s][j]);
      float y = fmaxf(a2r[j]*x + c2r[j], 0.f);
      mx = fmaxf(mx, y);
    }
    mx = fmaxf(mx, __shfl_xor(mx,1));
    mx = fmaxf(mx, __shfl_xor(mx,2));
    mx = fmaxf(mx, __shfl_xor(mx,4));
    if (j8 == 0) s_mx[s*32 + r32] = mx;
  }
  __syncthreads();
  // softmax over the 512 maxes
  red[t] = fmaxf(s_mx[t], s_mx[t+256]);
  __syncthreads();
  for (int s = 128; s > 0; s >>= 1){ if (t < s) red[t] = fmaxf(red[t], red[t+s]); __syncthreads(); }
  if (t == 0) sgmax = red[0];
  __syncthreads();
  float e0 = expf(s_mx[t] - sgmax), e1 = expf(s_mx[t+256] - sgmax);
  s_aw[t] = e0; s_aw[t+256] = e1;
  red[t] = e0 + e1;
  __syncthreads();
  for (int s = 128; s > 0; s >>= 1){ if (t < s) red[t] += red[t+s]; __syncthreads(); }
  if (t == 0) sinvS = 1.0f / red[0];
  __syncthreads();
  // Pass C: weighted sum from registers (y recomputed; no second global read).
  float acc[8];
  #pragma unroll
  for (int j = 0; j < 8; ++j) acc[j] = 0.f;
  #pragma unroll
  for (int s = 0; s < 16; ++s){
    float aw = s_aw[s*32 + r32];   // unnormalized e^(.)
    #pragma unroll
    for (int j = 0; j < 8; ++j){
      float x = bf2f((unsigned short)xv[s][j]);
      float y = fmaxf(a2r[j]*x + c2r[j], 0.f);
      acc[j] += aw*y;
    }
  }
  #pragma unroll
  for (int j = 0; j < 8; ++j) part[r32*64 + c0 + j] = acc[j];
  __syncthreads();
  if (t < 64){
    float a = 0.f;
    #pragma unroll 8
    for (int r = 0; r < 32; ++r) a += part[r*64 + t];
    s_att[t] = a * sinvS;   // normalize once at the end
  }
  __syncthreads();
  if (t < 32){
    float z = M1b[t];
    #pragma unroll 8
    for (int c = 0; c < 64; ++c) z += s_att[c]*M1w[c*32 + t];
    ws[WS_Z + bn*32 + t] = z;
    int rep = blk & 15;
    atomicAdd(&ws[WS_ST3 + rep*64 + t], z);
    atomicAdd(&ws[WS_ST3 + rep*64 + 32 + t], z*z);
  }
}

// ---------------- K6: BN3 + head L2 -> logits ----------------
__global__ __launch_bounds__(256) void k6(const float* __restrict__ M1g,
    const float* __restrict__ M1be, const float* __restrict__ M2w,
    const float* __restrict__ M2b, const float* __restrict__ ws, float* __restrict__ out){
  int t = threadIdx.x; int s = blockIdx.x*256 + t;
  __shared__ float sa3[32], sc3[32];
  if (t < 32){
    float su = 0.f, q = 0.f;
    #pragma unroll
    for (int r = 0; r < 16; ++r){ su += ws[WS_ST3 + r*64 + t]; q += ws[WS_ST3 + r*64 + 32 + t]; }
    float mu = su/P3, var = q/P3 - mu*mu;
    float istd = rsqrtf(var + 1e-5f);
    float A3 = M1g[t]*istd;
    sa3[t] = A3; sc3[t] = M1be[t] - mu*A3;
  }
  __syncthreads();
  float a0 = M2b[0], a1 = M2b[1];
  #pragma unroll
  for (int j = 0; j < 32; ++j){
    float y = fmaxf(ws[WS_Z + s*32 + j]*sa3[j] + sc3[j], 0.f);
    a0 += y*M2w[j*2+0]; a1 += y*M2w[j*2+1];
  }
  out[s*2+0] = a0; out[s*2+1] = a1;
}

extern "C" void kernel_launch(void* const* d_in, const int* in_sizes, int n_in,
                              void* d_out, int out_size, void* d_ws, size_t ws_size,
                              hipStream_t stream){
  const float* wxyz = (const float*)d_in[0];
  const float* wpts = (const float*)d_in[1];
  const float* rf3  = (const float*)d_in[2];
  const float* rf3i = (const float*)d_in[3];
  const float* lz   = (const float*)d_in[4];
  const float* W1   = (const float*)d_in[5];
  const float* b1   = (const float*)d_in[6];
  const float* g1   = (const float*)d_in[7];
  const float* be1  = (const float*)d_in[8];
  const float* W2   = (const float*)d_in[9];
  const float* g2   = (const float*)d_in[11];
  const float* be2  = (const float*)d_in[12];
  const float* M1w  = (const float*)d_in[13];
  const float* M1b  = (const float*)d_in[14];
  const float* M1g  = (const float*)d_in[15];
  const float* M1be = (const float*)d_in[16];
  const float* M2w  = (const float*)d_in[17];
  const float* M2b  = (const float*)d_in[18];
  float* ws  = (float*)d_ws;
  float* out = (float*)d_out;
  // zero colmax (encoded-min) + BN stat accumulators (ws is poisoned 0xAA each call)
  hipMemsetAsync(ws + WS_CMAX, 0, (1024 + 4096 + 2048 + 1024)*sizeof(float), stream);
  k1a<<<1024,128,0,stream>>>(wxyz, wpts, lz, W1, ws);
  k1b<<<1024,128,0,stream>>>(rf3, rf3i, W1, ws);
  k2 <<<1024,256,0,stream>>>(ws);
  k3 <<<1024,128,0,stream>>>(wxyz, W1, b1, ws);
  k4 <<<4096,256,0,stream>>>(wxyz, W1, b1, g1, be1, W2, ws);
  k5 <<<1024,256,0,stream>>>(g2, be2, M1w, M1b, ws);
  k6 <<<4,256,0,stream>>>(M1g, M1be, M2w, M2b, ws, out);
}

// Round 3
// 239.261 us; speedup vs baseline: 1.2887x; 1.0350x over previous
//
#include <hip/hip_runtime.h>
#include <hip/hip_bf16.h>

// Problem constants (B,N,H,W,C) = (2,512,16,32,64)
#define B_ 2
#define N_ 512
#define M_ 512
#define C_ 64
#define O1 128
#define O2 64
#define O3 32
#define PBIG 524288.0f   // B*N*M samples for BN1/BN2
#define P3   1024.0f     // B*N samples for BN3

typedef short s8v __attribute__((ext_vector_type(8)));   // 8 bf16 (4 VGPRs)
typedef float f4v __attribute__((ext_vector_type(4)));   // MFMA accumulator

// ---- workspace layout (float-element offsets). Total ~71 MB (same as before). ----
#define WS_SRCN 0        //  [B][N][64]   (dead after k2 -> reused as WS_P0)
#define WS_DSTN 65536    //  [B][M][64]   (dead after k2 -> reused as WS_P0)
#define WS_P0   0        //  [B*N][128] BN1-folded per-(b,n) part (written in k3b)
#define WS_U    131072   //  [B][N][128]
#define WS_V    262144   //  [B][M][128]  (scaled by A1 in k3b, in place)
#define WS_DXY  393216   //  [B][M][2]
#define WS_COS  395264   //  [B][N][M]
#define WS_RMAX 919552   //  [B*N]
#define WS_CMAX 920576   //  [B*M] (uint, order-encoded max)
#define WS_ST1  921600   //  [16][256] BN1 partial sums
#define WS_ST2  925696   //  [16][128] BN2 partial sums
#define WS_ST3  927744   //  [16][64]  BN3 partial sums
#define WS_Z    928768   //  [B][N][32]  (written by k5; overlaps W2F which is dead by then)
#define WS_W2F  928768   //  bf16 [4][4][64][8] fragment-packed W2 (k3b -> k4)
#define WS_W9S  932864   //  [3][128] A1-scaled W1 rank-1 columns (k3b -> k4)
#define WS_X2   961536   //  bf16 [B][N][M][64] starts here

__device__ __forceinline__ unsigned fenc(float f){
  unsigned b = __float_as_uint(f);
  return (b & 0x80000000u) ? ~b : (b | 0x80000000u);
}
__device__ __forceinline__ float fdec(unsigned u){
  unsigned b = (u & 0x80000000u) ? (u & 0x7fffffffu) : ~u;
  return __uint_as_float(b);
}
__device__ __forceinline__ unsigned short f2bf(float f){
  unsigned u = __float_as_uint(f);
  unsigned r = (u + 0x7fffu + ((u >> 16) & 1u)) >> 16;   // RNE
  return (unsigned short)r;
}
__device__ __forceinline__ float bf2f(unsigned short h){
  return __uint_as_float(((unsigned)h) << 16);
}
// pack two f32 -> bf16x2 by truncation: one v_perm_b32
__device__ __forceinline__ unsigned pk_trunc(float lo, float hi){
  return __builtin_amdgcn_perm(__float_as_uint(hi), __float_as_uint(lo), 0x07060302u);
}
__device__ __forceinline__ f4v relu4(f4v z){
  z[0] = fmaxf(z[0], 0.f); z[1] = fmaxf(z[1], 0.f);
  z[2] = fmaxf(z[2], 0.f); z[3] = fmaxf(z[3], 0.f);
  return z;
}

// ---------------- K1a: per-(b,n) src normals + U ----------------
__global__ __launch_bounds__(128) void k1a(const float* __restrict__ wxyz,
    const float* __restrict__ wpts, const float* __restrict__ lz,
    const float* __restrict__ W1, float* __restrict__ ws){
  int blk = blockIdx.x; int b = blk >> 9, n = blk & 511; int t = threadIdx.x;
  int bn = b*N_ + n;
  __shared__ float wp[64]; __shared__ float sxyz[3]; __shared__ float slz; __shared__ float srn;
  if (t < 64) wp[t] = wpts[bn*64 + t];
  if (t >= 64 && t < 67) sxyz[t-64] = wxyz[bn*3 + (t-64)];
  if (t == 67) slz = lz[bn];
  __syncthreads();
  if (t < 64){
    float v = wp[t]*wp[t];
    v += __shfl_down(v,32); v += __shfl_down(v,16); v += __shfl_down(v,8);
    v += __shfl_down(v,4);  v += __shfl_down(v,2);  v += __shfl_down(v,1);
    if (t == 0) srn = 1.0f / fmaxf(sqrtf(v), 1e-12f);
  }
  __syncthreads();
  if (t < 64) ws[WS_SRCN + bn*64 + t] = wp[t]*srn;
  int o = t;
  float x = sxyz[0], y = sxyz[1], z = sxyz[2], l = slz;
  float acc = x*l*W1[0*O1+o] + y*l*W1[1*O1+o] + z*l*W1[2*O1+o]
            + wp[0]*W1[3*O1+o] + wp[1]*W1[4*O1+o]
            + x*W1[7*O1+o] + y*W1[8*O1+o];
  #pragma unroll 8
  for (int c = 0; c < 64; ++c) acc += wp[c]*W1[(10+c)*O1+o];
  ws[WS_U + bn*O1 + o] = acc;
}

// ---------------- K1b: per-(b,m) dst normals + V + dst_xy ----------------
__global__ __launch_bounds__(128) void k1b(const float* __restrict__ rf3,
    const float* __restrict__ rf3i, const float* __restrict__ W1, float* __restrict__ ws){
  int blk = blockIdx.x; int b = blk >> 9, m = blk & 511; int t = threadIdx.x;
  int bm = b*M_ + m;
  __shared__ float rf[64]; __shared__ float sdx, sdy, srn;
  if (t < 64) rf[t] = rf3[(b*64 + t)*512 + m];
  if (t == 64) sdx = rf3i[(b*3 + 0)*512 + m];
  if (t == 65) sdy = rf3i[(b*3 + 1)*512 + m];
  __syncthreads();
  if (t < 64){
    float v = rf[t]*rf[t];
    v += __shfl_down(v,32); v += __shfl_down(v,16); v += __shfl_down(v,8);
    v += __shfl_down(v,4);  v += __shfl_down(v,2);  v += __shfl_down(v,1);
    if (t == 0) srn = 1.0f / fmaxf(sqrtf(v), 1e-12f);
  }
  __syncthreads();
  if (t < 64) ws[WS_DSTN + bm*64 + t] = rf[t]*srn;
  if (t == 0){ ws[WS_DXY + bm*2+0] = sdx; ws[WS_DXY + bm*2+1] = sdy; }
  int o = t;
  float acc = sdx*(W1[5*O1+o] - W1[7*O1+o]) + sdy*(W1[6*O1+o] - W1[8*O1+o]);
  #pragma unroll 8
  for (int c = 0; c < 64; ++c) acc += rf[c]*W1[(74+c)*O1+o];
  ws[WS_V + bm*O1 + o] = acc;
}

// ---------------- K2: cos matrix + rowmax + colmax(atomic), all 256 threads ----------------
__global__ __launch_bounds__(256) void k2(float* __restrict__ ws){
  int blk = blockIdx.x; int b = blk >> 9, n = blk & 511; int t = threadIdx.x;
  int bn = b*N_ + n;
  __shared__ __align__(16) float sn[64];
  __shared__ float dnt[64*65];   // +1 pad: conflict-free row reads
  __shared__ float part[4*64];
  if (t < 64) sn[t] = ws[WS_SRCN + bn*64 + t];
  unsigned* cmax = (unsigned*)ws + WS_CMAX;
  float lmax = -1e30f;
  for (int chunk = 0; chunk < 8; ++chunk){
    __syncthreads();
    const float4* src = (const float4*)(ws + WS_DSTN + (size_t)(b*M_ + chunk*64)*64);
    #pragma unroll
    for (int i = 0; i < 4; ++i){
      float4 v = src[t + i*256];
      int base = (t + i*256)*4; int mm = base >> 6, c = base & 63;
      float* dp = &dnt[mm*65 + c];
      dp[0]=v.x; dp[1]=v.y; dp[2]=v.z; dp[3]=v.w;
    }
    __syncthreads();
    {
      int mm = t & 63, cg = t >> 6;
      const float* dr = &dnt[mm*65 + cg*16];
      const float* sr = &sn[cg*16];
      float p = 0.f;
      #pragma unroll
      for (int k = 0; k < 16; ++k) p += sr[k]*dr[k];
      part[cg*64 + mm] = p;
    }
    __syncthreads();
    if (t < 64){
      float d = part[t] + part[64+t] + part[128+t] + part[192+t];
      int m = chunk*64 + t;
      ws[WS_COS + bn*M_ + m] = d;
      atomicMax(&cmax[b*M_ + m], fenc(d));
      lmax = fmaxf(lmax, d);
    }
  }
  if (t < 64){
    lmax = fmaxf(lmax, __shfl_xor(lmax,32)); lmax = fmaxf(lmax, __shfl_xor(lmax,16));
    lmax = fmaxf(lmax, __shfl_xor(lmax,8));  lmax = fmaxf(lmax, __shfl_xor(lmax,4));
    lmax = fmaxf(lmax, __shfl_xor(lmax,2));  lmax = fmaxf(lmax, __shfl_xor(lmax,1));
    if (t == 0) ws[WS_RMAX + bn] = lmax;
  }
}

// ---------------- K3: BN1 stats via rank-structured recompute (256 thr: o x m-half) ----
__global__ __launch_bounds__(256) void k3(const float* __restrict__ wxyz,
    const float* __restrict__ W1, const float* __restrict__ b1, float* __restrict__ ws){
  int blk = blockIdx.x; int b = blk >> 9, n = blk & 511; int t = threadIdx.x;
  int bn = b*N_ + n;
  __shared__ float s_en[512], s_s1[512], s_s2[512];
  __shared__ float sx, sy, srm;
  if (t == 0){ sx = wxyz[bn*3+0]; sy = wxyz[bn*3+1]; srm = ws[WS_RMAX+bn]; }
  __syncthreads();
  const unsigned* cmax = (const unsigned*)ws + WS_CMAX;
  #pragma unroll
  for (int i = 0; i < 2; ++i){
    int m = t + i*256;
    float dx = ws[WS_DXY + (b*M_+m)*2+0], dy = ws[WS_DXY + (b*M_+m)*2+1];
    float ex = sx-dx, ey = sy-dy;
    s_en[m] = sqrtf(ex*ex + ey*ey);
    float cv = ws[WS_COS + bn*M_ + m];
    s_s1[m] = cv/(srm + 1e-6f);
    s_s2[m] = cv/(fdec(cmax[b*M_+m]) + 1e-10f);
  }
  __syncthreads();
  int o = t & 127, mh = t >> 7;
  float u  = ws[WS_U + bn*O1 + o] + b1[o];
  float w9 = W1[9*O1+o], wa = W1[138*O1+o], wb = W1[139*O1+o];
  float sum = 0.f, ssq = 0.f;
  const float* Vp = ws + WS_V + b*M_*O1 + o;
  int mBeg = mh*256, mEnd = mBeg + 256;
  #pragma unroll 8
  for (int m = mBeg; m < mEnd; ++m){
    float xv = u + Vp[m*O1] + s_en[m]*w9 + s_s1[m]*wa + s_s2[m]*wb;
    sum += xv; ssq += xv*xv;
  }
  int rep = blk & 15;
  atomicAdd(&ws[WS_ST1 + rep*256 + o], sum);
  atomicAdd(&ws[WS_ST1 + rep*256 + 128 + o], ssq);
}

// ---------------- K3b: finalize BN1 -> P0 per (b,n); scale V by A1; pack W2 frags ----
__global__ __launch_bounds__(128) void k3b(const float* __restrict__ W1,
    const float* __restrict__ b1, const float* __restrict__ g1,
    const float* __restrict__ be1, const float* __restrict__ W2, float* __restrict__ ws){
  int blk = blockIdx.x; int t = threadIdx.x;
  int o = t;
  float s = 0.f, q = 0.f;
  #pragma unroll
  for (int r = 0; r < 16; ++r){ s += ws[WS_ST1 + r*256 + o]; q += ws[WS_ST1 + r*256 + 128 + o]; }
  float mu = s/PBIG, var = q/PBIG - mu*mu;
  float istd = rsqrtf(var + 1e-5f);
  float A1 = g1[o]*istd, C1 = be1[o] - mu*A1;
  if (blk < 1024){                       // P0[bn][o]
    int bn = blk;
    ws[WS_P0 + bn*O1 + o] = (ws[WS_U + bn*O1 + o] + b1[o])*A1 + C1;
  } else if (blk < 1040){                // V *= A1, 64 rows per block
    int r0 = (blk - 1024)*64;
    for (int r = 0; r < 64; ++r)
      ws[WS_V + (size_t)(r0 + r)*O1 + o] *= A1;
  } else {                               // scaled rank-1 cols + W2 fragment pack
    ws[WS_W9S + o]       = W1[9*O1+o]*A1;
    ws[WS_W9S + 128 + o] = W1[138*O1+o]*A1;
    ws[WS_W9S + 256 + o] = W1[139*O1+o]*A1;
    unsigned short* wf = (unsigned short*)(ws + WS_W2F);
    for (int i = t; i < 8192; i += 128){
      int j = i & 7, ll = (i >> 3) & 63, ct = (i >> 9) & 3, k0q = i >> 11;
      int oo = k0q*32 + (ll >> 4)*8 + j, c = ct*16 + (ll & 15);
      wf[i] = f2bf(W2[oo*O2 + c]);
    }
  }
}

// ---------------- K4: h built in registers (A-frag order) -> MFMA -> x2(bf16) + BN2 stats ----
// MFMA operands swapped (W2 as A, h as B): D row=channel, col=m -> coalesced dwordx2 stores.
__global__ __launch_bounds__(256, 4) void k4(const float* __restrict__ wxyz,
    float* __restrict__ ws){
  int blk = blockIdx.x;
  int b = blk >> 11; int rem = blk & 2047; int n = rem >> 2; int mc = rem & 3;
  int t = threadIdx.x; int bn = b*N_ + n; int m0 = mc*128;
  __shared__ __align__(16) unsigned short wBf[8192];        // 16 KB fragment-packed W2
  __shared__ __align__(16) float p0s[128], w9s[128], was[128], wbs[128];
  __shared__ float s_en[128], s_s1[128], s_s2[128];
  __shared__ float ls[64], lq[64];
  __shared__ float sx, sy, srm;
  if (t == 0){ sx = wxyz[bn*3+0]; sy = wxyz[bn*3+1]; srm = ws[WS_RMAX+bn]; }
  if (t < 64){ ls[t] = 0.f; lq[t] = 0.f; }
  {   // stage W2 fragments: 1024 x 16B, lane-consecutive (conflict-free)
    const s8v* g = (const s8v*)(ws + WS_W2F);
    s8v* l = (s8v*)wBf;
    #pragma unroll
    for (int c2 = 0; c2 < 4; ++c2) l[c2*256 + t] = g[c2*256 + t];
  }
  if (t < 128){
    p0s[t] = ws[WS_P0 + bn*O1 + t];
    w9s[t] = ws[WS_W9S + t];
    was[t] = ws[WS_W9S + 128 + t];
    wbs[t] = ws[WS_W9S + 256 + t];
  }
  __syncthreads();
  if (t < 128){
    int m = m0 + t;
    float dx = ws[WS_DXY + (b*M_+m)*2+0], dy = ws[WS_DXY + (b*M_+m)*2+1];
    float ex = sx-dx, ey = sy-dy;
    s_en[t] = sqrtf(ex*ex + ey*ey);
    float cv = ws[WS_COS + bn*M_ + m];
    s_s1[t] = cv/(srm + 1e-6f);
    s_s2[t] = cv/(fdec(((const unsigned*)ws)[WS_CMAX + b*M_+m]) + 1e-10f);
  }
  __syncthreads();
  int ll = t & 63, w = t >> 6, l16 = ll & 15, quad = ll >> 4;
  int mb = m0 + w*32;
  float en0 = s_en[w*32 + l16],     s10 = s_s1[w*32 + l16],     s20 = s_s2[w*32 + l16];
  float en1 = s_en[w*32 + 16 + l16], s11 = s_s1[w*32 + 16 + l16], s21 = s_s2[w*32 + 16 + l16];
  f4v acc[2][4];
  #pragma unroll
  for (int i = 0; i < 2; ++i)
    #pragma unroll
    for (int j = 0; j < 4; ++j) acc[i][j] = (f4v){0.f,0.f,0.f,0.f};
  const float* Vb = ws + WS_V + (size_t)(b*M_ + mb)*O1;
  union U8 { s8v v; unsigned u[4]; };
  #pragma unroll
  for (int k0q = 0; k0q < 4; ++k0q){
    int ko = k0q*32 + quad*8;
    f4v p0a = *(const f4v*)&p0s[ko], p0b = *(const f4v*)&p0s[ko+4];
    f4v w9a = *(const f4v*)&w9s[ko], w9b = *(const f4v*)&w9s[ko+4];
    f4v waa = *(const f4v*)&was[ko], wab = *(const f4v*)&was[ko+4];
    f4v wba = *(const f4v*)&wbs[ko], wbb = *(const f4v*)&wbs[ko+4];
    s8v af[2];
    #pragma unroll
    for (int mt = 0; mt < 2; ++mt){
      const float* vp = Vb + (size_t)(mt*16 + l16)*O1 + ko;
      f4v va = *(const f4v*)vp, vb = *(const f4v*)(vp+4);
      float en = mt ? en1 : en0, s1 = mt ? s11 : s10, s2 = mt ? s21 : s20;
      f4v za = relu4(p0a + va + en*w9a + s1*waa + s2*wba);
      f4v zb = relu4(p0b + vb + en*w9b + s1*wab + s2*wbb);
      U8 u8;
      u8.u[0] = pk_trunc(za[0], za[1]);
      u8.u[1] = pk_trunc(za[2], za[3]);
      u8.u[2] = pk_trunc(zb[0], zb[1]);
      u8.u[3] = pk_trunc(zb[2], zb[3]);
      af[mt] = u8.v;
    }
    #pragma unroll
    for (int ct = 0; ct < 4; ++ct){
      s8v bb = *(const s8v*)&wBf[((k0q*4 + ct)*64 + ll)*8];
      acc[0][ct] = __builtin_amdgcn_mfma_f32_16x16x32_bf16(bb, af[0], acc[0][ct], 0,0,0);
      acc[1][ct] = __builtin_amdgcn_mfma_f32_16x16x32_bf16(bb, af[1], acc[1][ct], 0,0,0);
    }
  }
  // epilogue: coalesced stores (lane holds 4 consecutive channels for one m)
  unsigned short* x2p = (unsigned short*)(ws + WS_X2) + (size_t)bn*M_*O2;
  #pragma unroll
  for (int ct = 0; ct < 4; ++ct){
    int c0 = ct*16 + quad*4;
    #pragma unroll
    for (int mt = 0; mt < 2; ++mt){
      int m = mb + mt*16 + l16;
      uint2 uv;
      uv.x = (unsigned)f2bf(acc[mt][ct][0]) | ((unsigned)f2bf(acc[mt][ct][1]) << 16);
      uv.y = (unsigned)f2bf(acc[mt][ct][2]) | ((unsigned)f2bf(acc[mt][ct][3]) << 16);
      *(uint2*)(x2p + (size_t)m*O2 + c0) = uv;
    }
    #pragma unroll
    for (int r = 0; r < 4; ++r){
      float s = acc[0][ct][r] + acc[1][ct][r];
      float q = acc[0][ct][r]*acc[0][ct][r] + acc[1][ct][r]*acc[1][ct][r];
      s += __shfl_xor(s,1); s += __shfl_xor(s,2); s += __shfl_xor(s,4); s += __shfl_xor(s,8);
      q += __shfl_xor(q,1); q += __shfl_xor(q,2); q += __shfl_xor(q,4); q += __shfl_xor(q,8);
      if (l16 == 0){ atomicAdd(&ls[c0 + r], s); atomicAdd(&lq[c0 + r], q); }
    }
  }
  __syncthreads();
  int rep = blk & 15;
  if (t < 64) atomicAdd(&ws[WS_ST2 + rep*128 + t], ls[t]);
  else if (t < 128) atomicAdd(&ws[WS_ST2 + rep*128 + t], lq[t-64]);
}

// ---------------- K5: BN2 + softmax-attention pool + head L1 + BN3 stats ----------------
// x2 tile held in registers: thread owns 8 channels x 32 rows (16 x 16B loads).
__global__ __launch_bounds__(256) void k5(const float* __restrict__ g2,
    const float* __restrict__ be2, const float* __restrict__ M1w,
    const float* __restrict__ M1b, float* __restrict__ ws){
  int blk = blockIdx.x; int b = blk >> 9, n = blk & 511; int t = threadIdx.x;
  int bn = b*N_ + n;
  __shared__ float sa2[64], sc2[64];
  __shared__ float s_mx[512];
  __shared__ float s_aw[512];
  __shared__ float red[256];
  __shared__ float part[32*64];
  __shared__ float s_att[64];
  __shared__ float sgmax, sinvS;
  if (t < 64){
    float s = 0.f, q = 0.f;
    #pragma unroll
    for (int r = 0; r < 16; ++r){ s += ws[WS_ST2 + r*128 + t]; q += ws[WS_ST2 + r*128 + 64 + t]; }
    float mu = s/PBIG, var = q/PBIG - mu*mu;
    float istd = rsqrtf(var + 1e-5f);
    float A2 = g2[t]*istd;
    sa2[t] = A2; sc2[t] = be2[t] - mu*A2;
  }
  __syncthreads();
  int j8 = t & 7, r32 = t >> 3;
  int c0 = j8*8;
  float a2r[8], c2r[8];
  #pragma unroll
  for (int j = 0; j < 8; ++j){ a2r[j] = sa2[c0+j]; c2r[j] = sc2[c0+j]; }
  const unsigned short* xp = (const unsigned short*)(ws + WS_X2) + (size_t)bn*M_*O2;
  s8v xv[16];
  #pragma unroll
  for (int s = 0; s < 16; ++s)
    xv[s] = *(const s8v*)(xp + (size_t)(s*32 + r32)*64 + c0);
  #pragma unroll
  for (int s = 0; s < 16; ++s){
    float mx = 0.f;  // relu output >= 0
    #pragma unroll
    for (int j = 0; j < 8; ++j){
      float x = bf2f((unsigned short)xv[s][j]);
      float y = fmaxf(a2r[j]*x + c2r[j], 0.f);
      mx = fmaxf(mx, y);
    }
    mx = fmaxf(mx, __shfl_xor(mx,1));
    mx = fmaxf(mx, __shfl_xor(mx,2));
    mx = fmaxf(mx, __shfl_xor(mx,4));
    if (j8 == 0) s_mx[s*32 + r32] = mx;
  }
  __syncthreads();
  red[t] = fmaxf(s_mx[t], s_mx[t+256]);
  __syncthreads();
  for (int s = 128; s > 0; s >>= 1){ if (t < s) red[t] = fmaxf(red[t], red[t+s]); __syncthreads(); }
  if (t == 0) sgmax = red[0];
  __syncthreads();
  float e0 = expf(s_mx[t] - sgmax), e1 = expf(s_mx[t+256] - sgmax);
  s_aw[t] = e0; s_aw[t+256] = e1;
  red[t] = e0 + e1;
  __syncthreads();
  for (int s = 128; s > 0; s >>= 1){ if (t < s) red[t] += red[t+s]; __syncthreads(); }
  if (t == 0) sinvS = 1.0f / red[0];
  __syncthreads();
  float acc[8];
  #pragma unroll
  for (int j = 0; j < 8; ++j) acc[j] = 0.f;
  #pragma unroll
  for (int s = 0; s < 16; ++s){
    float aw = s_aw[s*32 + r32];   // unnormalized e^(.)
    #pragma unroll
    for (int j = 0; j < 8; ++j){
      float x = bf2f((unsigned short)xv[s][j]);
      float y = fmaxf(a2r[j]*x + c2r[j], 0.f);
      acc[j] += aw*y;
    }
  }
  #pragma unroll
  for (int j = 0; j < 8; ++j) part[r32*64 + c0 + j] = acc[j];
  __syncthreads();
  if (t < 64){
    float a = 0.f;
    #pragma unroll 8
    for (int r = 0; r < 32; ++r) a += part[r*64 + t];
    s_att[t] = a * sinvS;
  }
  __syncthreads();
  if (t < 32){
    float z = M1b[t];
    #pragma unroll 8
    for (int c = 0; c < 64; ++c) z += s_att[c]*M1w[c*32 + t];
    ws[WS_Z + bn*32 + t] = z;
    int rep = blk & 15;
    atomicAdd(&ws[WS_ST3 + rep*64 + t], z);
    atomicAdd(&ws[WS_ST3 + rep*64 + 32 + t], z*z);
  }
}

// ---------------- K6: BN3 + head L2 -> logits ----------------
__global__ __launch_bounds__(256) void k6(const float* __restrict__ M1g,
    const float* __restrict__ M1be, const float* __restrict__ M2w,
    const float* __restrict__ M2b, const float* __restrict__ ws, float* __restrict__ out){
  int t = threadIdx.x; int s = blockIdx.x*256 + t;
  __shared__ float sa3[32], sc3[32];
  if (t < 32){
    float su = 0.f, q = 0.f;
    #pragma unroll
    for (int r = 0; r < 16; ++r){ su += ws[WS_ST3 + r*64 + t]; q += ws[WS_ST3 + r*64 + 32 + t]; }
    float mu = su/P3, var = q/P3 - mu*mu;
    float istd = rsqrtf(var + 1e-5f);
    float A3 = M1g[t]*istd;
    sa3[t] = A3; sc3[t] = M1be[t] - mu*A3;
  }
  __syncthreads();
  float a0 = M2b[0], a1 = M2b[1];
  #pragma unroll
  for (int j = 0; j < 32; ++j){
    float y = fmaxf(ws[WS_Z + s*32 + j]*sa3[j] + sc3[j], 0.f);
    a0 += y*M2w[j*2+0]; a1 += y*M2w[j*2+1];
  }
  out[s*2+0] = a0; out[s*2+1] = a1;
}

extern "C" void kernel_launch(void* const* d_in, const int* in_sizes, int n_in,
                              void* d_out, int out_size, void* d_ws, size_t ws_size,
                              hipStream_t stream){
  const float* wxyz = (const float*)d_in[0];
  const float* wpts = (const float*)d_in[1];
  const float* rf3  = (const float*)d_in[2];
  const float* rf3i = (const float*)d_in[3];
  const float* lz   = (const float*)d_in[4];
  const float* W1   = (const float*)d_in[5];
  const float* b1   = (const float*)d_in[6];
  const float* g1   = (const float*)d_in[7];
  const float* be1  = (const float*)d_in[8];
  const float* W2   = (const float*)d_in[9];
  const float* g2   = (const float*)d_in[11];
  const float* be2  = (const float*)d_in[12];
  const float* M1w  = (const float*)d_in[13];
  const float* M1b  = (const float*)d_in[14];
  const float* M1g  = (const float*)d_in[15];
  const float* M1be = (const float*)d_in[16];
  const float* M2w  = (const float*)d_in[17];
  const float* M2b  = (const float*)d_in[18];
  float* ws  = (float*)d_ws;
  float* out = (float*)d_out;
  // zero colmax (encoded-min) + BN stat accumulators (contiguous range)
  hipMemsetAsync(ws + WS_CMAX, 0, (1024 + 4096 + 2048 + 1024)*sizeof(float), stream);
  k1a<<<1024,128,0,stream>>>(wxyz, wpts, lz, W1, ws);
  k1b<<<1024,128,0,stream>>>(rf3, rf3i, W1, ws);
  k2 <<<1024,256,0,stream>>>(ws);
  k3 <<<1024,256,0,stream>>>(wxyz, W1, b1, ws);
  k3b<<<1041,128,0,stream>>>(W1, b1, g1, be1, W2, ws);
  k4 <<<4096,256,0,stream>>>(wxyz, ws);
  k5 <<<1024,256,0,stream>>>(g2, be2, M1w, M1b, ws);
  k6 <<<4,256,0,stream>>>(M1g, M1be, M2w, M2b, ws, out);
}